// Round 6
// baseline (135.191 us; speedup 1.0000x reference)
//
#include <hip/hip_runtime.h>
#include <stdint.h>

typedef unsigned short ushort_t;
typedef __attribute__((ext_vector_type(4))) float f32x4;
typedef __attribute__((ext_vector_type(8))) short short8;
typedef __attribute__((ext_vector_type(4))) ushort_t us4;

#define LDS_AS __attribute__((address_space(3)))
#define GLB_AS __attribute__((address_space(1)))

__device__ __forceinline__ ushort_t f2bf(float f) {
    uint32_t u = __float_as_uint(f);
    u += 0x7FFFu + ((u >> 16) & 1u);   // RNE
    return (ushort_t)(u >> 16);
}

__device__ __forceinline__ float bf2f(ushort_t u) {
    return __uint_as_float(((uint32_t)u) << 16);
}

__device__ __forceinline__ float dpp_shr1(float x) {   // lane l <- lane l-1 (wave_shr:1)
    return __int_as_float(__builtin_amdgcn_update_dpp(
        __float_as_int(1e30f), __float_as_int(x), 0x138, 0xF, 0xF, false));
}

// ---------- prep: all row-normalizations -> bf16; ONE WAVE PER ROW (no block barriers) ----
// rows [0,8192): frame->Abf | [8192,12288): cand->Bbf | [12288,12416): video->Z[0:128)
// [12416,12544): sent->Z[128:256) | [12544,12672): mean(cand_b)->Z[256:384)
__global__ __launch_bounds__(256) void k_prep_all(
    const float* __restrict__ frame, const float* __restrict__ cand,
    const float* __restrict__ video, const float* __restrict__ sent,
    ushort_t* __restrict__ Abf, ushort_t* __restrict__ Bbf, ushort_t* __restrict__ Zbf)
{
    const int w = threadIdx.x >> 6, ln = threadIdx.x & 63;
    const int r = blockIdx.x * 4 + w;
    float4 x0, x1, x2;
    ushort_t* dst;
    if (r < 8192) {
        const float4* s = (const float4*)(frame + (size_t)r * 768);
        x0 = s[ln]; x1 = s[ln + 64]; x2 = s[ln + 128];
        dst = Abf + (size_t)r * 768;
    } else if (r < 12288) {
        int q = r - 8192;
        const float4* s = (const float4*)(cand + (size_t)q * 768);
        x0 = s[ln]; x1 = s[ln + 64]; x2 = s[ln + 128];
        dst = Bbf + (size_t)q * 768;
    } else if (r < 12416) {
        int q = r - 12288;
        const float4* s = (const float4*)(video + (size_t)q * 768);
        x0 = s[ln]; x1 = s[ln + 64]; x2 = s[ln + 128];
        dst = Zbf + (size_t)q * 768;
    } else if (r < 12544) {
        int q = r - 12416;
        const float4* s = (const float4*)(sent + (size_t)q * 768);
        x0 = s[ln]; x1 = s[ln + 64]; x2 = s[ln + 128];
        dst = Zbf + (size_t)(128 + q) * 768;
    } else {
        int b = r - 12544;
        x0 = x1 = x2 = make_float4(0.f, 0.f, 0.f, 0.f);
        for (int k = 0; k < 32; ++k) {
            const float4* s = (const float4*)(cand + (size_t)(b * 32 + k) * 768);
            float4 y0 = s[ln], y1 = s[ln + 64], y2 = s[ln + 128];
            x0.x += y0.x; x0.y += y0.y; x0.z += y0.z; x0.w += y0.w;
            x1.x += y1.x; x1.y += y1.y; x1.z += y1.z; x1.w += y1.w;
            x2.x += y2.x; x2.y += y2.y; x2.z += y2.z; x2.w += y2.w;
        }
        const float s32 = 1.0f / 32.0f;
        x0.x *= s32; x0.y *= s32; x0.z *= s32; x0.w *= s32;
        x1.x *= s32; x1.y *= s32; x1.z *= s32; x1.w *= s32;
        x2.x *= s32; x2.y *= s32; x2.z *= s32; x2.w *= s32;
        dst = Zbf + (size_t)(256 + b) * 768;
    }
    float ss = x0.x*x0.x + x0.y*x0.y + x0.z*x0.z + x0.w*x0.w
             + x1.x*x1.x + x1.y*x1.y + x1.z*x1.z + x1.w*x1.w
             + x2.x*x2.x + x2.y*x2.y + x2.z*x2.z + x2.w*x2.w;
    #pragma unroll
    for (int off = 32; off > 0; off >>= 1) ss += __shfl_xor(ss, off);
    float sc = 1.0f / fmaxf(sqrtf(ss), 1e-12f);
    us4 u0, u1, u2;
    u0.x = f2bf(x0.x * sc); u0.y = f2bf(x0.y * sc); u0.z = f2bf(x0.z * sc); u0.w = f2bf(x0.w * sc);
    u1.x = f2bf(x1.x * sc); u1.y = f2bf(x1.y * sc); u1.z = f2bf(x1.z * sc); u1.w = f2bf(x1.w * sc);
    u2.x = f2bf(x2.x * sc); u2.y = f2bf(x2.y * sc); u2.z = f2bf(x2.z * sc); u2.w = f2bf(x2.w * sc);
    us4* d4 = (us4*)dst;
    d4[ln] = u0; d4[ln + 64] = u1; d4[ln + 128] = u2;
}

// ---------- Gram: G = 10 * Z @ Z^T, Z=[vn;tn;an] 384x768 bf16, G f32 384x384 ----------
__global__ __launch_bounds__(256) void k_gram(const ushort_t* __restrict__ Z, float* __restrict__ G)
{
    __shared__ __align__(16) ushort_t As[128 * 64];
    __shared__ __align__(16) ushort_t Bs[128 * 64];
    const int t = threadIdx.x;
    const int lane = t & 63, w = t >> 6;
    const int wr = w >> 1, wc = w & 1;
    const int m0 = blockIdx.x * 128, n0 = blockIdx.y * 128;
    const int lr = lane & 15, lk = lane >> 4;

    f32x4 acc[4][4] = {};

    for (int k0 = 0; k0 < 768; k0 += 64) {
        #pragma unroll
        for (int ii = 0; ii < 4; ++ii) {
            int idx = ii * 256 + t;
            int row = idx >> 3, kc = (idx & 7) * 8;
            __builtin_amdgcn_global_load_lds(
                (const GLB_AS void*)(Z + (size_t)(m0 + row) * 768 + (k0 + kc)),
                (LDS_AS void*)(As + idx * 8), 16, 0, 0);
        }
        #pragma unroll
        for (int ii = 0; ii < 4; ++ii) {
            int idx = ii * 256 + t;
            int row = idx >> 3, kc = (idx & 7) * 8;
            __builtin_amdgcn_global_load_lds(
                (const GLB_AS void*)(Z + (size_t)(n0 + row) * 768 + (k0 + kc)),
                (LDS_AS void*)(Bs + idx * 8), 16, 0, 0);
        }
        __syncthreads();
        #pragma unroll
        for (int kk = 0; kk < 2; ++kk) {
            short8 av[4], bv[4];
            #pragma unroll
            for (int f = 0; f < 4; ++f)
                av[f] = *(const short8*)(As + (wr * 64 + f * 16 + lr) * 64 + kk * 32 + lk * 8);
            #pragma unroll
            for (int f = 0; f < 4; ++f)
                bv[f] = *(const short8*)(Bs + (wc * 64 + f * 16 + lr) * 64 + kk * 32 + lk * 8);
            #pragma unroll
            for (int fr = 0; fr < 4; ++fr)
                #pragma unroll
                for (int fc = 0; fc < 4; ++fc)
                    acc[fr][fc] = __builtin_amdgcn_mfma_f32_16x16x32_bf16(av[fr], bv[fc], acc[fr][fc], 0, 0, 0);
        }
        __syncthreads();
    }
    #pragma unroll
    for (int fr = 0; fr < 4; ++fr)
        #pragma unroll
        for (int fc = 0; fc < 4; ++fc) {
            int col = n0 + wc * 64 + fc * 16 + lr;
            #pragma unroll
            for (int q = 0; q < 4; ++q) {
                int row = m0 + wr * 64 + fr * 16 + lk * 4 + q;
                G[(size_t)row * 384 + col] = 10.0f * acc[fr][fc][q];
            }
        }
}

// ---------- all LSEs from G (col-LSE of block (a,b) = row-LSE of block (b,a)) ----------
__global__ __launch_bounds__(256) void k_lse(const float* __restrict__ G, float* __restrict__ lse)
{
    const int w = threadIdx.x >> 6, ln = threadIdx.x & 63;
    const int tid = blockIdx.x * 4 + w;
    int row, c0, nc, maskc = -1;
    if      (tid < 128) { row = tid;       c0 = 128; nc = 128; }
    else if (tid < 256) { row = tid;       c0 = 0;   nc = 128; }
    else if (tid < 384) { row = tid - 256; c0 = 256; nc = 128; }
    else if (tid < 512) { row = tid - 128; c0 = 0;   nc = 128; }
    else if (tid < 640) { row = tid - 384; c0 = 256; nc = 128; }
    else if (tid < 768) { row = tid - 384; c0 = 128; nc = 128; }
    else                { row = tid - 768; c0 = 0;   nc = 256; maskc = tid - 768; }
    const float* g = G + (size_t)row * 384 + c0;
    const int cnt = nc >> 6;
    float vals[4];
    #pragma unroll
    for (int q = 0; q < 4; ++q) {
        int c = q * 64 + ln;
        vals[q] = (q < cnt) ? g[c] : -1e30f;
        if (c == maskc) vals[q] = -1e30f;       // NT self-mask (c0==0 there)
    }
    float m = fmaxf(fmaxf(vals[0], vals[1]), fmaxf(vals[2], vals[3]));
    #pragma unroll
    for (int off = 32; off > 0; off >>= 1) m = fmaxf(m, __shfl_xor(m, off));
    float s = 0.f;
    #pragma unroll
    for (int q = 0; q < 4; ++q) s += expf(vals[q] - m);
    #pragma unroll
    for (int off = 32; off > 0; off >>= 1) s += __shfl_xor(s, off);
    if (ln == 0) lse[tid] = m + logf(s);
}

// ---------- FUSED 256x256 GEMM, phase-interleaved (T3-style) + soft-DTW ----------
// 8 waves (2M x 4N), per-wave C = 128x64, BK=64, 12 K-tiles, 2 LDS dbufs (128 KB).
// Per K-tile: 4 quadrant-phases (qm,qn), 16 MFMA each; A-frags held in regs across
// the 2 qn-phases -> 32 ds_read_b128 / K-tile / wave (LDS : MFMA ~ 1:1).
// 3-bit chunk-XOR swizzle (chunk ^= row&7) applied on the GLOBAL source (linear LDS
// dest, rule: gload_lds writes base+lane*16) and on the ds_read chunk -> all-bank spread.
// Staging: tile t+1's 4 halves issued at phases 0,0,1,1 of tile t; single vmcnt(0)
// drain per tile at phase 3 (panels are L2-resident; drain ~free), barrier after.
// DTW tail: acc -> per-wave transposed LDS [64 cols][132], two interleaved 95-step chains.
__global__ __launch_bounds__(512, 2) void k_gemm_dtw(
    const ushort_t* __restrict__ A, const ushort_t* __restrict__ B,
    float* __restrict__ Dm)
{
    __shared__ __align__(16) ushort_t lds[67584];   // 135168 B; staging = [0, 65536) elems
    const int t = threadIdx.x;
    const int lane = t & 63, w = t >> 6;            // 8 waves
    const int wr = w >> 2, wc = w & 3;              // 2M x 4N
    const int lr = lane & 15, lk = lane >> 4;
    const int chx0 = ((0 + lk) ^ (lr & 7)) * 8;     // kk=0 chunk offset (elems)
    const int chx1 = ((4 + lk) ^ (lr & 7)) * 8;     // kk=1
    // XCD swizzle: each XCD owns a 4-M-tile strip (A panel ~1.5 MB -> L2-resident)
    const int lin = blockIdx.x;
    const int xcd = lin & 7, idx = lin >> 3;
    const int m0 = (xcd * 4 + (idx & 3)) * 256;
    const int n0 = (idx >> 2) * 256;

    f32x4 acc[8][4] = {};
    short8 av[4][2];

    // stage half h of K-tile `tile` into dbuf[tile&1]: h0/h1 = A rows 0-127/128-255,
    // h2/h3 = B rows 0-127/128-255. 2 loads/thread; LDS dest linear, source pre-swizzled.
#define STAGEH(tile, h) { \
    ushort_t* dst_ = lds + ((tile) & 1) * 32768 + (h) * 8192; \
    const ushort_t* sm_ = ((h) < 2) ? A : B; \
    const int gr0_ = (((h) < 2) ? m0 : n0) + ((h) & 1) * 128; \
    { int s_ = t;       int row_ = s_ >> 3, c_ = s_ & 7; \
      __builtin_amdgcn_global_load_lds( \
        (const GLB_AS void*)(sm_ + (size_t)(gr0_ + row_) * 768 + (tile) * 64 + ((c_ ^ (row_ & 7)) * 8)), \
        (LDS_AS void*)(dst_ + s_ * 8), 16, 0, 0); } \
    { int s_ = 512 + t; int row_ = s_ >> 3, c_ = s_ & 7; \
      __builtin_amdgcn_global_load_lds( \
        (const GLB_AS void*)(sm_ + (size_t)(gr0_ + row_) * 768 + (tile) * 64 + ((c_ ^ (row_ & 7)) * 8)), \
        (LDS_AS void*)(dst_ + s_ * 8), 16, 0, 0); } \
}

    // one quadrant-phase: (qm,qn); READA=1 -> load av for qm; stages per ST0/ST1 flags
#define PHASE(tt, qm, qn, READA, H0, H1, DOVM) { \
    const ushort_t* ab_ = lds + ((tt) & 1) * 32768; \
    const ushort_t* bb_ = ab_ + 16384; \
    if (READA) { \
        _Pragma("unroll") \
        for (int mf = 0; mf < 4; ++mf) { \
            av[mf][0] = *(const short8*)(ab_ + (wr * 128 + (qm) * 64 + mf * 16 + lr) * 64 + chx0); \
            av[mf][1] = *(const short8*)(ab_ + (wr * 128 + (qm) * 64 + mf * 16 + lr) * 64 + chx1); \
        } \
    } \
    short8 bv[2][2]; \
    _Pragma("unroll") \
    for (int nf = 0; nf < 2; ++nf) { \
        bv[nf][0] = *(const short8*)(bb_ + (wc * 64 + (qn) * 32 + nf * 16 + lr) * 64 + chx0); \
        bv[nf][1] = *(const short8*)(bb_ + (wc * 64 + (qn) * 32 + nf * 16 + lr) * 64 + chx1); \
    } \
    if ((H0) >= 0 && (tt) < 11) STAGEH((tt) + 1, (H0)); \
    if ((H1) >= 0 && (tt) < 11) STAGEH((tt) + 1, (H1)); \
    __builtin_amdgcn_sched_barrier(0); \
    __builtin_amdgcn_s_barrier(); \
    asm volatile("s_waitcnt lgkmcnt(0)" ::: "memory"); \
    __builtin_amdgcn_sched_barrier(0); \
    __builtin_amdgcn_s_setprio(1); \
    _Pragma("unroll") \
    for (int mf = 0; mf < 4; ++mf) \
        _Pragma("unroll") \
        for (int nf = 0; nf < 2; ++nf) { \
            acc[(qm)*4+mf][(qn)*2+nf] = __builtin_amdgcn_mfma_f32_16x16x32_bf16(av[mf][0], bv[nf][0], acc[(qm)*4+mf][(qn)*2+nf], 0, 0, 0); \
            acc[(qm)*4+mf][(qn)*2+nf] = __builtin_amdgcn_mfma_f32_16x16x32_bf16(av[mf][1], bv[nf][1], acc[(qm)*4+mf][(qn)*2+nf], 0, 0, 0); \
        } \
    __builtin_amdgcn_s_setprio(0); \
    if (DOVM && (tt) < 11) asm volatile("s_waitcnt vmcnt(0)" ::: "memory"); \
    __builtin_amdgcn_s_barrier(); \
    __builtin_amdgcn_sched_barrier(0); \
}

    // prologue: stage tile 0 fully, drain, sync
    STAGEH(0, 0) STAGEH(0, 1) STAGEH(0, 2) STAGEH(0, 3)
    asm volatile("s_waitcnt vmcnt(0)" ::: "memory");
    __builtin_amdgcn_s_barrier();

    #pragma unroll 1
    for (int tt = 0; tt < 12; ++tt) {
        PHASE(tt, 0, 0, 1, 0, 1, 0)    // read av(qm0); stage t+1 halves A0,A1
        PHASE(tt, 0, 1, 0, 2, 3, 0)    // reuse av;     stage t+1 halves B0,B1
        PHASE(tt, 1, 0, 1, -1, -1, 0)  // read av(qm1)
        PHASE(tt, 1, 1, 0, -1, -1, 1)  // reuse av; drain staging once per tile
    }
#undef PHASE
#undef STAGEH

    // ---- acc (sim) -> per-wave transposed LDS tile [64 cols][stride 132] ----
    ushort_t* dtwT = lds + w * 8448;                // 8 x 8448 = 67584 elems
    #pragma unroll
    for (int nf = 0; nf < 4; ++nf)
        #pragma unroll
        for (int mf = 0; mf < 8; ++mf) {
            us4 pk;
            pk.x = f2bf(acc[mf][nf][0]); pk.y = f2bf(acc[mf][nf][1]);
            pk.z = f2bf(acc[mf][nf][2]); pk.w = f2bf(acc[mf][nf][3]);
            *(us4*)(dtwT + (nf * 16 + lr) * 132 + mf * 16 + lk * 4) = pk;
        }

    // ---- soft-DTW: two interleaved chains (video-b rows 0-63 / 64-127) ----
    const float K10 = 14.4269504088896340f;   // 10*log2(e): mul-free softmin in scaled space
    const float BIG = 1e30f;
    const int j = lane & 31, pr = lane >> 5;
    const bool isj0 = (j == 0);
    const ushort_t* base = dtwT + lane * 132;  // this lane's column
    float rpA = BIG, rp2A = BIG, rpB = BIG, rp2B = BIG;
    float dg0 = 0.0f;

    #pragma unroll 5
    for (int s = 0; s < 95; ++s) {
        float upA = dpp_shr1(rpA), dgA = dpp_shr1(rp2A);
        float upB = dpp_shr1(rpB), dgB = dpp_shr1(rp2B);
        if (isj0) { upA = BIG; dgA = dg0; upB = BIG; dgB = dg0; }
        int ii = s - j;
        int iic = ii < 0 ? 0 : (ii > 63 ? 63 : ii);
        float cA = fmaf(bf2f(base[iic]), -K10, K10);        // K10*(1-sim)
        float cB = fmaf(bf2f(base[64 + iic]), -K10, K10);
        float mnA, mdA, mxA, mnB, mdB, mxB;
        asm("v_min3_f32 %0, %1, %2, %3" : "=v"(mnA) : "v"(rpA), "v"(upA), "v"(dgA));
        asm("v_med3_f32 %0, %1, %2, %3" : "=v"(mdA) : "v"(rpA), "v"(upA), "v"(dgA));
        asm("v_max3_f32 %0, %1, %2, %3" : "=v"(mxA) : "v"(rpA), "v"(upA), "v"(dgA));
        asm("v_min3_f32 %0, %1, %2, %3" : "=v"(mnB) : "v"(rpB), "v"(upB), "v"(dgB));
        asm("v_med3_f32 %0, %1, %2, %3" : "=v"(mdB) : "v"(rpB), "v"(upB), "v"(dgB));
        asm("v_max3_f32 %0, %1, %2, %3" : "=v"(mxB) : "v"(rpB), "v"(upB), "v"(dgB));
        float eA = __builtin_amdgcn_exp2f(mnA - mdA) + __builtin_amdgcn_exp2f(mnA - mxA);
        float eB = __builtin_amdgcn_exp2f(mnB - mdB) + __builtin_amdgcn_exp2f(mnB - mxB);
        float rA = cA + mnA - __builtin_amdgcn_logf(1.0f + eA);   // v_log_f32 = log2
        float rB = cB + mnB - __builtin_amdgcn_logf(1.0f + eB);
        bool act = (unsigned)ii < 64u;
        rp2A = act ? rpA : rp2A; rpA = act ? rA : rpA;
        rp2B = act ? rpB : rp2B; rpB = act ? rB : rpB;
        dg0 = BIG;
    }
    if (j == 31) {   // lanes 31 (pr=0) and 63 (pr=1) hold R[63][31] of each chain
        int b0 = (m0 >> 6) + wr * 2;              // video batch (chain A; +1 = chain B)
        int bp = (n0 >> 5) + wc * 2 + pr;         // text batch
        Dm[(size_t)b0 * 128 + bp]       = rpA * (1.0f / K10);
        Dm[(size_t)(b0 + 1) * 128 + bp] = rpB * (1.0f / K10);
    }
}

// ---------- finalize: CE losses (from G diag + lse) + DTW CE -> scalar ----------
__global__ __launch_bounds__(128) void k_finalize(
    const float* __restrict__ G, const float* __restrict__ lse,
    const float* __restrict__ Dm, float* __restrict__ out)
{
    int i = threadIdx.x;
    float d1 = G[(size_t)i * 384 + 128 + i];
    float d3 = G[(size_t)i * 384 + 256 + i];
    float d4 = G[(size_t)(128 + i) * 384 + 256 + i];
    float l1 = 0.5f * ((lse[i] - d1) + (lse[128 + i] - d1));
    float l3 = 0.5f * ((lse[256 + i] - d3) + (lse[384 + i] - d3));
    float l4 = 0.5f * ((lse[512 + i] - d4) + (lse[640 + i] - d4));
    float nt = 0.5f * (lse[768 + i] - d1) + 0.5f * (lse[896 + i] - d1);
    float mxr = -1e30f, mxc = -1e30f;
    for (int jj = 0; jj < 128; ++jj) {
        mxr = fmaxf(mxr, -10.0f * Dm[i * 128 + jj]);
        mxc = fmaxf(mxc, -10.0f * Dm[jj * 128 + i]);
    }
    float sr = 0.f, sc2 = 0.f;
    for (int jj = 0; jj < 128; ++jj) {
        sr  += expf(-10.0f * Dm[i * 128 + jj] - mxr);
        sc2 += expf(-10.0f * Dm[jj * 128 + i] - mxc);
    }
    float dd = -10.0f * Dm[i * 128 + i];
    float ld = 0.5f * ((mxr + logf(sr) - dd) + (mxc + logf(sc2) - dd));
    float tot = l1 + l3 + l4 + nt + 0.1f * ld;
    #pragma unroll
    for (int o = 32; o > 0; o >>= 1) tot += __shfl_down(tot, o);
    __shared__ float sm[2];
    if ((i & 63) == 0) sm[i >> 6] = tot;
    __syncthreads();
    if (i == 0) out[0] = (sm[0] + sm[1]) / (128.0f * 5.0f);
}

extern "C" void kernel_launch(void* const* d_in, const int* in_sizes, int n_in,
                              void* d_out, int out_size, void* d_ws, size_t ws_size,
                              hipStream_t stream)
{
    (void)in_sizes; (void)n_in; (void)out_size; (void)ws_size;
    const float* video = (const float*)d_in[0];   // [128,768]
    const float* sent  = (const float*)d_in[1];   // [128,768]
    const float* cand  = (const float*)d_in[2];   // [128,32,768]
    const float* frame = (const float*)d_in[3];   // [128,64,768]
    // d_in[4] = pos_step: unused by the reference.

    char* ws = (char*)d_ws;
    size_t off = 0;
    auto alloc = [&](size_t b) { void* p = ws + off; off = (off + b + 255) & ~(size_t)255; return p; };
    ushort_t* Abf = (ushort_t*)alloc((size_t)8192 * 768 * 2);
    ushort_t* Bbf = (ushort_t*)alloc((size_t)4096 * 768 * 2);
    ushort_t* Zbf = (ushort_t*)alloc((size_t)384 * 768 * 2);
    float*    G   = (float*)alloc((size_t)384 * 384 * 4);
    float*    lse = (float*)alloc((size_t)1024 * 4);
    float*    Dm  = (float*)alloc((size_t)128 * 128 * 4);

    k_prep_all <<<3168, 256, 0, stream>>>(frame, cand, video, sent, Abf, Bbf, Zbf);
    k_gemm_dtw <<<512, 512, 0, stream>>>(Abf, Bbf, Dm);
    k_gram     <<<dim3(3, 3), 256, 0, stream>>>(Zbf, G);
    k_lse      <<<256, 256, 0, stream>>>(G, lse);
    k_finalize <<<1, 128, 0, stream>>>(G, lse, Dm, (float*)d_out);
}

// Round 7
// 134.011 us; speedup vs baseline: 1.0088x; 1.0088x over previous
//
#include <hip/hip_runtime.h>
#include <stdint.h>

typedef unsigned short ushort_t;
typedef __attribute__((ext_vector_type(4))) float f32x4;
typedef __attribute__((ext_vector_type(8))) short short8;
typedef __attribute__((ext_vector_type(4))) ushort_t us4;

#define LDS_AS __attribute__((address_space(3)))
#define GLB_AS __attribute__((address_space(1)))

__device__ __forceinline__ ushort_t f2bf(float f) {
    uint32_t u = __float_as_uint(f);
    u += 0x7FFFu + ((u >> 16) & 1u);   // RNE
    return (ushort_t)(u >> 16);
}

__device__ __forceinline__ float bf2f(ushort_t u) {
    return __uint_as_float(((uint32_t)u) << 16);
}

__device__ __forceinline__ float dpp_shr1(float x) {   // lane l <- lane l-1 (wave_shr:1)
    return __int_as_float(__builtin_amdgcn_update_dpp(
        __float_as_int(1e30f), __float_as_int(x), 0x138, 0xF, 0xF, false));
}

// ---------- prep: all row-normalizations -> bf16; ONE WAVE PER ROW ----------
__global__ __launch_bounds__(256) void k_prep_all(
    const float* __restrict__ frame, const float* __restrict__ cand,
    const float* __restrict__ video, const float* __restrict__ sent,
    ushort_t* __restrict__ Abf, ushort_t* __restrict__ Bbf, ushort_t* __restrict__ Zbf)
{
    const int w = threadIdx.x >> 6, ln = threadIdx.x & 63;
    const int r = blockIdx.x * 4 + w;
    float4 x0, x1, x2;
    ushort_t* dst;
    if (r < 8192) {
        const float4* s = (const float4*)(frame + (size_t)r * 768);
        x0 = s[ln]; x1 = s[ln + 64]; x2 = s[ln + 128];
        dst = Abf + (size_t)r * 768;
    } else if (r < 12288) {
        int q = r - 8192;
        const float4* s = (const float4*)(cand + (size_t)q * 768);
        x0 = s[ln]; x1 = s[ln + 64]; x2 = s[ln + 128];
        dst = Bbf + (size_t)q * 768;
    } else if (r < 12416) {
        int q = r - 12288;
        const float4* s = (const float4*)(video + (size_t)q * 768);
        x0 = s[ln]; x1 = s[ln + 64]; x2 = s[ln + 128];
        dst = Zbf + (size_t)q * 768;
    } else if (r < 12544) {
        int q = r - 12416;
        const float4* s = (const float4*)(sent + (size_t)q * 768);
        x0 = s[ln]; x1 = s[ln + 64]; x2 = s[ln + 128];
        dst = Zbf + (size_t)(128 + q) * 768;
    } else {
        int b = r - 12544;
        x0 = x1 = x2 = make_float4(0.f, 0.f, 0.f, 0.f);
        for (int k = 0; k < 32; ++k) {
            const float4* s = (const float4*)(cand + (size_t)(b * 32 + k) * 768);
            float4 y0 = s[ln], y1 = s[ln + 64], y2 = s[ln + 128];
            x0.x += y0.x; x0.y += y0.y; x0.z += y0.z; x0.w += y0.w;
            x1.x += y1.x; x1.y += y1.y; x1.z += y1.z; x1.w += y1.w;
            x2.x += y2.x; x2.y += y2.y; x2.z += y2.z; x2.w += y2.w;
        }
        const float s32 = 1.0f / 32.0f;
        x0.x *= s32; x0.y *= s32; x0.z *= s32; x0.w *= s32;
        x1.x *= s32; x1.y *= s32; x1.z *= s32; x1.w *= s32;
        x2.x *= s32; x2.y *= s32; x2.z *= s32; x2.w *= s32;
        dst = Zbf + (size_t)(256 + b) * 768;
    }
    float ss = x0.x*x0.x + x0.y*x0.y + x0.z*x0.z + x0.w*x0.w
             + x1.x*x1.x + x1.y*x1.y + x1.z*x1.z + x1.w*x1.w
             + x2.x*x2.x + x2.y*x2.y + x2.z*x2.z + x2.w*x2.w;
    #pragma unroll
    for (int off = 32; off > 0; off >>= 1) ss += __shfl_xor(ss, off);
    float sc = 1.0f / fmaxf(sqrtf(ss), 1e-12f);
    us4 u0, u1, u2;
    u0.x = f2bf(x0.x * sc); u0.y = f2bf(x0.y * sc); u0.z = f2bf(x0.z * sc); u0.w = f2bf(x0.w * sc);
    u1.x = f2bf(x1.x * sc); u1.y = f2bf(x1.y * sc); u1.z = f2bf(x1.z * sc); u1.w = f2bf(x1.w * sc);
    u2.x = f2bf(x2.x * sc); u2.y = f2bf(x2.y * sc); u2.z = f2bf(x2.z * sc); u2.w = f2bf(x2.w * sc);
    us4* d4 = (us4*)dst;
    d4[ln] = u0; d4[ln + 64] = u1; d4[ln + 128] = u2;
}

// ---------- Gram: G = 10 * Z @ Z^T, Z=[vn;tn;an] 384x768 bf16, G f32 384x384 ----------
__global__ __launch_bounds__(256) void k_gram(const ushort_t* __restrict__ Z, float* __restrict__ G)
{
    __shared__ __align__(16) ushort_t As[128 * 64];
    __shared__ __align__(16) ushort_t Bs[128 * 64];
    const int t = threadIdx.x;
    const int lane = t & 63, w = t >> 6;
    const int wr = w >> 1, wc = w & 1;
    const int m0 = blockIdx.x * 128, n0 = blockIdx.y * 128;
    const int lr = lane & 15, lk = lane >> 4;

    f32x4 acc[4][4] = {};

    for (int k0 = 0; k0 < 768; k0 += 64) {
        #pragma unroll
        for (int ii = 0; ii < 4; ++ii) {
            int idx = ii * 256 + t;
            int row = idx >> 3, kc = (idx & 7) * 8;
            __builtin_amdgcn_global_load_lds(
                (const GLB_AS void*)(Z + (size_t)(m0 + row) * 768 + (k0 + kc)),
                (LDS_AS void*)(As + idx * 8), 16, 0, 0);
        }
        #pragma unroll
        for (int ii = 0; ii < 4; ++ii) {
            int idx = ii * 256 + t;
            int row = idx >> 3, kc = (idx & 7) * 8;
            __builtin_amdgcn_global_load_lds(
                (const GLB_AS void*)(Z + (size_t)(n0 + row) * 768 + (k0 + kc)),
                (LDS_AS void*)(Bs + idx * 8), 16, 0, 0);
        }
        __syncthreads();
        #pragma unroll
        for (int kk = 0; kk < 2; ++kk) {
            short8 av[4], bv[4];
            #pragma unroll
            for (int f = 0; f < 4; ++f)
                av[f] = *(const short8*)(As + (wr * 64 + f * 16 + lr) * 64 + kk * 32 + lk * 8);
            #pragma unroll
            for (int f = 0; f < 4; ++f)
                bv[f] = *(const short8*)(Bs + (wc * 64 + f * 16 + lr) * 64 + kk * 32 + lk * 8);
            #pragma unroll
            for (int fr = 0; fr < 4; ++fr)
                #pragma unroll
                for (int fc = 0; fc < 4; ++fc)
                    acc[fr][fc] = __builtin_amdgcn_mfma_f32_16x16x32_bf16(av[fr], bv[fc], acc[fr][fc], 0, 0, 0);
        }
        __syncthreads();
    }
    #pragma unroll
    for (int fr = 0; fr < 4; ++fr)
        #pragma unroll
        for (int fc = 0; fc < 4; ++fc) {
            int col = n0 + wc * 64 + fc * 16 + lr;
            #pragma unroll
            for (int q = 0; q < 4; ++q) {
                int row = m0 + wr * 64 + fr * 16 + lk * 4 + q;
                G[(size_t)row * 384 + col] = 10.0f * acc[fr][fc][q];
            }
        }
}

// ---------- all LSEs from G (col-LSE of block (a,b) = row-LSE of block (b,a)) ----------
__global__ __launch_bounds__(256) void k_lse(const float* __restrict__ G, float* __restrict__ lse)
{
    const int w = threadIdx.x >> 6, ln = threadIdx.x & 63;
    const int tid = blockIdx.x * 4 + w;
    int row, c0, nc, maskc = -1;
    if      (tid < 128) { row = tid;       c0 = 128; nc = 128; }
    else if (tid < 256) { row = tid;       c0 = 0;   nc = 128; }
    else if (tid < 384) { row = tid - 256; c0 = 256; nc = 128; }
    else if (tid < 512) { row = tid - 128; c0 = 0;   nc = 128; }
    else if (tid < 640) { row = tid - 384; c0 = 256; nc = 128; }
    else if (tid < 768) { row = tid - 384; c0 = 128; nc = 128; }
    else                { row = tid - 768; c0 = 0;   nc = 256; maskc = tid - 768; }
    const float* g = G + (size_t)row * 384 + c0;
    const int cnt = nc >> 6;
    float vals[4];
    #pragma unroll
    for (int q = 0; q < 4; ++q) {
        int c = q * 64 + ln;
        vals[q] = (q < cnt) ? g[c] : -1e30f;
        if (c == maskc) vals[q] = -1e30f;       // NT self-mask (c0==0 there)
    }
    float m = fmaxf(fmaxf(vals[0], vals[1]), fmaxf(vals[2], vals[3]));
    #pragma unroll
    for (int off = 32; off > 0; off >>= 1) m = fmaxf(m, __shfl_xor(m, off));
    float s = 0.f;
    #pragma unroll
    for (int q = 0; q < 4; ++q) s += expf(vals[q] - m);
    #pragma unroll
    for (int off = 32; off > 0; off >>= 1) s += __shfl_xor(s, off);
    if (ln == 0) lse[tid] = m + logf(s);
}

// ---------- FUSED 256x256 GEMM (m201-faithful counted-vmcnt 4-phase) + soft-DTW ----------
// 8 waves (2M x 4N), per-wave C = 128x64, BK=64, 12 K-tiles.
// LDS: 2 dbufs x {A0,A1,B0,B1} half-tiles (128x64 each) = 128 KB.
// Per K-tile u, 4 quadrant-phases; stages: Ph1 A1(u+1), Ph2 B0(u+1), Ph3 B1(u+1),
// Ph4 A0(u+2). ONE counted s_waitcnt vmcnt(2) per tile (Ph4, after stage-issue,
// before barrier) -> collectively confirms tile u+1 one full phase before its first
// ds_read. vmcnt(0) only at tile 10 (epilogue drain); tile 11 peeled, no stages.
// B-frags for both qn kept in regs (bv0/bv1): 24 ds_read_b128 / K-tile / wave.
// chunk-XOR swizzle q = c ^ (row&7) on global source AND ds_read -> uniform 32-bank load.
// DTW tail: acc -> per-wave transposed LDS [64 cols][132], two interleaved 95-step chains.
__global__ __launch_bounds__(512, 2) void k_gemm_dtw(
    const ushort_t* __restrict__ A, const ushort_t* __restrict__ B,
    float* __restrict__ Dm)
{
    __shared__ __align__(16) ushort_t lds[67584];   // 135168 B (staging uses first 128 KB)
    const int t = threadIdx.x;
    const int lane = t & 63, w = t >> 6;            // 8 waves
    const int wr = w >> 2, wc = w & 3;              // 2M x 4N
    const int lr = lane & 15, lk = lane >> 4;
    const int chq0 = ((0 + lk) ^ (lr & 7)) * 8;     // kk=0 swizzled chunk (elems)
    const int chq1 = ((4 + lk) ^ (lr & 7)) * 8;     // kk=1
    // XCD swizzle: each XCD owns a 4-M-tile strip (A panel ~1.5 MB -> L2-resident)
    const int lin = blockIdx.x;
    const int xcd = lin & 7, idx = lin >> 3;
    const int m0 = (xcd * 4 + (idx & 3)) * 256;
    const int n0 = (idx >> 2) * 256;

    f32x4 acc[8][4] = {};
    short8 av[4][2], bv0[2][2], bv1[2][2];

    // stage half-tile (tile, mat, half): 128 rows x 64 k -> dbuf[tile&1]; 2 loads/thread.
    // LDS dest linear (slot*16B); global source chunk pre-swizzled: g = c ^ (row&7).
#define STAGE(tile, mat, half) { \
    ushort_t* dst_ = lds + ((tile) & 1) * 32768 + ((mat) * 2 + (half)) * 8192; \
    const ushort_t* src_ = (mat) ? B : A; \
    const int gb_ = ((mat) ? n0 : m0) + (half) * 128; \
    { int s_ = t;       int row_ = s_ >> 3, ch_ = s_ & 7; \
      __builtin_amdgcn_global_load_lds( \
        (const GLB_AS void*)(src_ + (size_t)(gb_ + row_) * 768 + (tile) * 64 + ((ch_ ^ (row_ & 7)) * 8)), \
        (LDS_AS void*)(dst_ + s_ * 8), 16, 0, 0); } \
    { int s_ = 512 + t; int row_ = s_ >> 3, ch_ = s_ & 7; \
      __builtin_amdgcn_global_load_lds( \
        (const GLB_AS void*)(src_ + (size_t)(gb_ + row_) * 768 + (tile) * 64 + ((ch_ ^ (row_ & 7)) * 8)), \
        (LDS_AS void*)(dst_ + s_ * 8), 16, 0, 0); } \
}

#define MFMA16(qm, qn, BV) \
    __builtin_amdgcn_s_setprio(1); \
    _Pragma("unroll") \
    for (int mf = 0; mf < 4; ++mf) \
        _Pragma("unroll") \
        for (int nf = 0; nf < 2; ++nf) { \
            acc[(qm)*4+mf][(qn)*2+nf] = __builtin_amdgcn_mfma_f32_16x16x32_bf16(av[mf][0], BV[nf][0], acc[(qm)*4+mf][(qn)*2+nf], 0, 0, 0); \
            acc[(qm)*4+mf][(qn)*2+nf] = __builtin_amdgcn_mfma_f32_16x16x32_bf16(av[mf][1], BV[nf][1], acc[(qm)*4+mf][(qn)*2+nf], 0, 0, 0); \
        } \
    __builtin_amdgcn_s_setprio(0);

#define PHASE_SYNC \
    __builtin_amdgcn_sched_barrier(0); \
    __builtin_amdgcn_s_barrier(); \
    asm volatile("s_waitcnt lgkmcnt(0)" ::: "memory"); \
    __builtin_amdgcn_sched_barrier(0);

    // one K-tile = 4 phases. VMN: 2 = counted, 0 = drain (tile 10), -1 = none (tile 11)
#define TILE(tt, DO_ST, DO_A0N, VMN) { \
    const ushort_t* ab = lds + ((tt) & 1) * 32768 + wr * 8192; \
    const ushort_t* bb = lds + ((tt) & 1) * 32768 + 16384 + (wc >> 1) * 8192 + (wc & 1) * 4096; \
    /* Ph1: read A(qm0)+B(qn0); stage A1(t+1) */ \
    _Pragma("unroll") for (int mf = 0; mf < 4; ++mf) { \
        av[mf][0] = *(const short8*)(ab + (mf * 16 + lr) * 64 + chq0); \
        av[mf][1] = *(const short8*)(ab + (mf * 16 + lr) * 64 + chq1); } \
    _Pragma("unroll") for (int nf = 0; nf < 2; ++nf) { \
        bv0[nf][0] = *(const short8*)(bb + (nf * 16 + lr) * 64 + chq0); \
        bv0[nf][1] = *(const short8*)(bb + (nf * 16 + lr) * 64 + chq1); } \
    if (DO_ST) STAGE((tt) + 1, 0, 1); \
    PHASE_SYNC \
    MFMA16(0, 0, bv0) \
    __builtin_amdgcn_s_barrier(); \
    /* Ph2: read B(qn1); stage B0(t+1) */ \
    _Pragma("unroll") for (int nf = 0; nf < 2; ++nf) { \
        bv1[nf][0] = *(const short8*)(bb + (32 + nf * 16 + lr) * 64 + chq0); \
        bv1[nf][1] = *(const short8*)(bb + (32 + nf * 16 + lr) * 64 + chq1); } \
    if (DO_ST) STAGE((tt) + 1, 1, 0); \
    PHASE_SYNC \
    MFMA16(0, 1, bv1) \
    __builtin_amdgcn_s_barrier(); \
    /* Ph3: read A(qm1); stage B1(t+1) */ \
    _Pragma("unroll") for (int mf = 0; mf < 4; ++mf) { \
        av[mf][0] = *(const short8*)(ab + (64 + mf * 16 + lr) * 64 + chq0); \
        av[mf][1] = *(const short8*)(ab + (64 + mf * 16 + lr) * 64 + chq1); } \
    if (DO_ST) STAGE((tt) + 1, 1, 1); \
    PHASE_SYNC \
    MFMA16(1, 0, bv0) \
    __builtin_amdgcn_s_barrier(); \
    /* Ph4: no reads; stage A0(t+2); counted vmcnt */ \
    if (DO_A0N) STAGE((tt) + 2, 0, 0); \
    if ((VMN) == 2)      asm volatile("s_waitcnt vmcnt(2)" ::: "memory"); \
    else if ((VMN) == 0) asm volatile("s_waitcnt vmcnt(0)" ::: "memory"); \
    PHASE_SYNC \
    MFMA16(1, 1, bv1) \
    __builtin_amdgcn_s_barrier(); \
}

    // prologue: tile0 all halves + A0(1); confirm tile0 (2 newest still in flight)
    STAGE(0, 0, 0) STAGE(0, 0, 1) STAGE(0, 1, 0) STAGE(0, 1, 1) STAGE(1, 0, 0)
    asm volatile("s_waitcnt vmcnt(2)" ::: "memory");
    __builtin_amdgcn_s_barrier();

    #pragma unroll 1
    for (int tt = 0; tt < 10; ++tt) TILE(tt, 1, 1, 2)
    TILE(10, 1, 0, 0)
    TILE(11, 0, 0, -1)
#undef TILE
#undef PHASE_SYNC
#undef MFMA16
#undef STAGE

    // ---- acc (sim) -> per-wave transposed LDS tile [64 cols][stride 132] ----
    ushort_t* dtwT = lds + w * 8448;                // 8 x 8448 = 67584 elems
    #pragma unroll
    for (int nf = 0; nf < 4; ++nf)
        #pragma unroll
        for (int mf = 0; mf < 8; ++mf) {
            us4 pk;
            pk.x = f2bf(acc[mf][nf][0]); pk.y = f2bf(acc[mf][nf][1]);
            pk.z = f2bf(acc[mf][nf][2]); pk.w = f2bf(acc[mf][nf][3]);
            *(us4*)(dtwT + (nf * 16 + lr) * 132 + mf * 16 + lk * 4) = pk;
        }

    // ---- soft-DTW: two interleaved chains (video-b rows 0-63 / 64-127) ----
    const float K10 = 14.4269504088896340f;   // 10*log2(e): mul-free softmin in scaled space
    const float BIG = 1e30f;
    const int j = lane & 31, pr = lane >> 5;
    const bool isj0 = (j == 0);
    const ushort_t* base = dtwT + lane * 132;  // this lane's column
    float rpA = BIG, rp2A = BIG, rpB = BIG, rp2B = BIG;
    float dg0 = 0.0f;

    #pragma unroll 5
    for (int s = 0; s < 95; ++s) {
        float upA = dpp_shr1(rpA), dgA = dpp_shr1(rp2A);
        float upB = dpp_shr1(rpB), dgB = dpp_shr1(rp2B);
        if (isj0) { upA = BIG; dgA = dg0; upB = BIG; dgB = dg0; }
        int ii = s - j;
        int iic = ii < 0 ? 0 : (ii > 63 ? 63 : ii);
        float cA = fmaf(bf2f(base[iic]), -K10, K10);        // K10*(1-sim)
        float cB = fmaf(bf2f(base[64 + iic]), -K10, K10);
        float mnA, mdA, mxA, mnB, mdB, mxB;
        asm("v_min3_f32 %0, %1, %2, %3" : "=v"(mnA) : "v"(rpA), "v"(upA), "v"(dgA));
        asm("v_med3_f32 %0, %1, %2, %3" : "=v"(mdA) : "v"(rpA), "v"(upA), "v"(dgA));
        asm("v_max3_f32 %0, %1, %2, %3" : "=v"(mxA) : "v"(rpA), "v"(upA), "v"(dgA));
        asm("v_min3_f32 %0, %1, %2, %3" : "=v"(mnB) : "v"(rpB), "v"(upB), "v"(dgB));
        asm("v_med3_f32 %0, %1, %2, %3" : "=v"(mdB) : "v"(rpB), "v"(upB), "v"(dgB));
        asm("v_max3_f32 %0, %1, %2, %3" : "=v"(mxB) : "v"(rpB), "v"(upB), "v"(dgB));
        float eA = __builtin_amdgcn_exp2f(mnA - mdA) + __builtin_amdgcn_exp2f(mnA - mxA);
        float eB = __builtin_amdgcn_exp2f(mnB - mdB) + __builtin_amdgcn_exp2f(mnB - mxB);
        float rA = cA + mnA - __builtin_amdgcn_logf(1.0f + eA);   // v_log_f32 = log2
        float rB = cB + mnB - __builtin_amdgcn_logf(1.0f + eB);
        bool act = (unsigned)ii < 64u;
        rp2A = act ? rpA : rp2A; rpA = act ? rA : rpA;
        rp2B = act ? rpB : rp2B; rpB = act ? rB : rpB;
        dg0 = BIG;
    }
    if (j == 31) {   // lanes 31 (pr=0) and 63 (pr=1) hold R[63][31] of each chain
        int b0 = (m0 >> 6) + wr * 2;              // video batch (chain A; +1 = chain B)
        int bp = (n0 >> 5) + wc * 2 + pr;         // text batch
        Dm[(size_t)b0 * 128 + bp]       = rpA * (1.0f / K10);
        Dm[(size_t)(b0 + 1) * 128 + bp] = rpB * (1.0f / K10);
    }
}

// ---------- finalize: CE losses (from G diag + lse) + DTW CE -> scalar ----------
__global__ __launch_bounds__(128) void k_finalize(
    const float* __restrict__ G, const float* __restrict__ lse,
    const float* __restrict__ Dm, float* __restrict__ out)
{
    int i = threadIdx.x;
    float d1 = G[(size_t)i * 384 + 128 + i];
    float d3 = G[(size_t)i * 384 + 256 + i];
    float d4 = G[(size_t)(128 + i) * 384 + 256 + i];
    float l1 = 0.5f * ((lse[i] - d1) + (lse[128 + i] - d1));
    float l3 = 0.5f * ((lse[256 + i] - d3) + (lse[384 + i] - d3));
    float l4 = 0.5f * ((lse[512 + i] - d4) + (lse[640 + i] - d4));
    float nt = 0.5f * (lse[768 + i] - d1) + 0.5f * (lse[896 + i] - d1);
    float mxr = -1e30f, mxc = -1e30f;
    for (int jj = 0; jj < 128; ++jj) {
        mxr = fmaxf(mxr, -10.0f * Dm[i * 128 + jj]);
        mxc = fmaxf(mxc, -10.0f * Dm[jj * 128 + i]);
    }
    float sr = 0.f, sc2 = 0.f;
    for (int jj = 0; jj < 128; ++jj) {
        sr  += expf(-10.0f * Dm[i * 128 + jj] - mxr);
        sc2 += expf(-10.0f * Dm[jj * 128 + i] - mxc);
    }
    float dd = -10.0f * Dm[i * 128 + i];
    float ld = 0.5f * ((mxr + logf(sr) - dd) + (mxc + logf(sc2) - dd));
    float tot = l1 + l3 + l4 + nt + 0.1f * ld;
    #pragma unroll
    for (int o = 32; o > 0; o >>= 1) tot += __shfl_down(tot, o);
    __shared__ float sm[2];
    if ((i & 63) == 0) sm[i >> 6] = tot;
    __syncthreads();
    if (i == 0) out[0] = (sm[0] + sm[1]) / (128.0f * 5.0f);
}

extern "C" void kernel_launch(void* const* d_in, const int* in_sizes, int n_in,
                              void* d_out, int out_size, void* d_ws, size_t ws_size,
                              hipStream_t stream)
{
    (void)in_sizes; (void)n_in; (void)out_size; (void)ws_size;
    const float* video = (const float*)d_in[0];   // [128,768]
    const float* sent  = (const float*)d_in[1];   // [128,768]
    const float* cand  = (const float*)d_in[2];   // [128,32,768]
    const float* frame = (const float*)d_in[3];   // [128,64,768]
    // d_in[4] = pos_step: unused by the reference.

    char* ws = (char*)d_ws;
    size_t off = 0;
    auto alloc = [&](size_t b) { void* p = ws + off; off = (off + b + 255) & ~(size_t)255; return p; };
    ushort_t* Abf = (ushort_t*)alloc((size_t)8192 * 768 * 2);
    ushort_t* Bbf = (ushort_t*)alloc((size_t)4096 * 768 * 2);
    ushort_t* Zbf = (ushort_t*)alloc((size_t)384 * 768 * 2);
    float*    G   = (float*)alloc((size_t)384 * 384 * 4);
    float*    lse = (float*)alloc((size_t)1024 * 4);
    float*    Dm  = (float*)alloc((size_t)128 * 128 * 4);

    k_prep_all <<<3168, 256, 0, stream>>>(frame, cand, video, sent, Abf, Bbf, Zbf);
    k_gemm_dtw <<<512, 512, 0, stream>>>(Abf, Bbf, Dm);
    k_gram     <<<dim3(3, 3), 256, 0, stream>>>(Zbf, G);
    k_lse      <<<256, 256, 0, stream>>>(G, lse);
    k_finalize <<<1, 128, 0, stream>>>(G, lse, Dm, (float*)d_out);
}